// Round 1
// baseline (295.470 us; speedup 1.0000x reference)
//
#include <hip/hip_runtime.h>

#define BB 32
#define CC 128
#define LL 4096
#define TD 512
#define KK 8
#define LOG2L 12
#define FF (LL/2+1)   // 2049
#define THREADS 256

// XOR swizzle: spreads stride-64 access patterns across banks.
__device__ __forceinline__ int SW(int i) { return i ^ ((i >> 6) & 63); }

// tab[j] = (cos(2*pi*j/L), sin(2*pi*j/L)), computed in fp64 for accuracy.
__global__ void build_table_k(float2* __restrict__ tab) {
    int j = blockIdx.x * blockDim.x + threadIdx.x;
    if (j < LL) {
        double th = (double)j * (6.283185307179586 / (double)LL);
        tab[j] = make_float2((float)cos(th), (float)sin(th));
    }
}

// g[b*C+c] = 1 + tanh(dot(time_emb[b], W[c]) + bias[c]); one wave per row.
__global__ void mod_k(const float* __restrict__ te, const float* __restrict__ W,
                      const float* __restrict__ bias, float* __restrict__ g) {
    int row = blockIdx.x;
    int b = row >> 7;      // / CC
    int c = row & (CC - 1);
    int l = threadIdx.x;   // 0..63
    const float* tp = te + b * TD;
    const float* wp = W + c * TD;
    float s = 0.f;
#pragma unroll
    for (int i = 0; i < TD / 64; ++i) s += tp[l + 64 * i] * wp[l + 64 * i];
#pragma unroll
    for (int off = 32; off; off >>= 1) s += __shfl_down(s, off);
    if (l == 0) g[row] = 1.0f + tanhf(s + bias[c]);
}

// One block per (b,c) row: modulate, 4096-pt FFT in LDS, top-8 |X|^2, then
// direct sparse inverse (8 sinusoids).
__global__ __launch_bounds__(THREADS)
void fft_topk_k(const float* __restrict__ x, const float* __restrict__ g,
                const float2* __restrict__ tab, float* __restrict__ out) {
    __shared__ float re[LL];
    __shared__ float im[LL];
    __shared__ float2 stab[LL];
    __shared__ float amp[FF];
    __shared__ float wval[THREADS / 64];
    __shared__ int   widx[THREADS / 64];
    __shared__ float selA[KK], selB[KK];
    __shared__ int   selF[KK];

    int row = blockIdx.x;
    int t = threadIdx.x;
    const float* xp = x + (size_t)row * LL;
    float gm = g[row];

    // stage trig table into LDS (coalesced)
    for (int i = t; i < LL; i += THREADS) stab[i] = tab[i];

    // load + modulate + bit-reverse into swizzled LDS (coalesced global read,
    // conflict-free LDS scatter thanks to SW())
    for (int i = t; i < LL; i += THREADS) {
        float v = xp[i] * gm;
        int r = __brev(i) >> (32 - LOG2L);
        int a = SW(r);
        re[a] = v;
        im[a] = 0.f;
    }

    // radix-2 DIT, 12 stages, natural-order output, numpy sign convention
    // (forward = e^{-2*pi*i*f*n/N})
    for (int s = 1; s <= LOG2L; ++s) {
        __syncthreads();
        int half = 1 << (s - 1);
        int tsh = LOG2L - s;
#pragma unroll 1
        for (int jj = t; jj < LL / 2; jj += THREADS) {
            int k = jj & (half - 1);
            int p1 = ((jj >> (s - 1)) << s) + k;
            int p2 = p1 + half;
            float2 cs = stab[k << tsh];  // w = (cs.x, -cs.y)
            int a1 = SW(p1), a2 = SW(p2);
            float vr = re[a2], vi = im[a2];
            float tr = cs.x * vr + cs.y * vi;   // wr*vr - wi*vi
            float ti = cs.x * vi - cs.y * vr;   // wr*vi + wi*vr
            float ur = re[a1], ui = im[a1];
            re[a1] = ur + tr; im[a1] = ui + ti;
            re[a2] = ur - tr; im[a2] = ui - ti;
        }
    }
    __syncthreads();

    // |X|^2 for bins 0..2048 (ordering identical to |X|)
    for (int f = t; f < FF; f += THREADS) {
        int a = SW(f);
        float rr = re[a], ii = im[a];
        amp[f] = rr * rr + ii * ii;
    }
    __syncthreads();

    // top-8 with ties -> lower index (matches lax.top_k)
    for (int it = 0; it < KK; ++it) {
        float bv = -1.0f; int bi2 = 1 << 30;
        for (int f = t; f < FF; f += THREADS) {
            float v = amp[f];
            if (v > bv) { bv = v; bi2 = f; }   // strict > keeps lowest index
        }
#pragma unroll
        for (int off = 32; off; off >>= 1) {
            float ov = __shfl_down(bv, off);
            int   oi = __shfl_down(bi2, off);
            if (ov > bv || (ov == bv && oi < bi2)) { bv = ov; bi2 = oi; }
        }
        if ((t & 63) == 0) { wval[t >> 6] = bv; widx[t >> 6] = bi2; }
        __syncthreads();
        if (t == 0) {
#pragma unroll
            for (int w2 = 1; w2 < THREADS / 64; ++w2) {
                if (wval[w2] > bv || (wval[w2] == bv && widx[w2] < bi2)) {
                    bv = wval[w2]; bi2 = widx[w2];
                }
            }
            selF[it] = bi2;
            float rr = re[SW(bi2)], ii = im[SW(bi2)];
            bool edge = (bi2 == 0) || (bi2 == LL / 2);
            float wgt = edge ? 1.0f : 2.0f;
            const float inv = 1.0f / (float)LL;
            selA[it] = wgt * inv * rr;
            selB[it] = edge ? 0.0f : wgt * inv * ii;  // pocketfft c2r ignores
                                                      // imag at DC/Nyquist
            amp[bi2] = -1.0f;  // remove from candidates
        }
        __syncthreads();
    }

    // sparse inverse: out[n] = sum_j A_j cos(2pi f_j n/L) - B_j sin(...)
    float sa[KK], sb[KK]; int sf[KK];
#pragma unroll
    for (int j = 0; j < KK; ++j) { sa[j] = selA[j]; sb[j] = selB[j]; sf[j] = selF[j]; }

    float* op = out + (size_t)row * LL;
    for (int i = t; i < LL; i += THREADS) {
        float acc = 0.f;
#pragma unroll
        for (int j = 0; j < KK; ++j) {
            int m = (sf[j] * i) & (LL - 1);   // exact integer range reduction
            float2 cs = stab[m];
            acc = fmaf(sa[j], cs.x, acc);
            acc = fmaf(-sb[j], cs.y, acc);
        }
        op[i] = acc;
    }
}

extern "C" void kernel_launch(void* const* d_in, const int* in_sizes, int n_in,
                              void* d_out, int out_size, void* d_ws, size_t ws_size,
                              hipStream_t stream) {
    const float* x    = (const float*)d_in[0];
    const float* te   = (const float*)d_in[1];
    const float* W    = (const float*)d_in[2];
    const float* bias = (const float*)d_in[3];
    float* out = (float*)d_out;

    float*  g   = (float*)d_ws;                     // 4096 floats = 16 KB
    float2* tab = (float2*)((char*)d_ws + 16384);   // 4096 float2 = 32 KB

    build_table_k<<<(LL + 255) / 256, 256, 0, stream>>>(tab);
    mod_k<<<BB * CC, 64, 0, stream>>>(te, W, bias, g);
    fft_topk_k<<<BB * CC, THREADS, 0, stream>>>(x, g, tab, out);
}

// Round 2
// 148.781 us; speedup vs baseline: 1.9859x; 1.9859x over previous
//
#include <hip/hip_runtime.h>

#define LL 4096
#define THREADS 256
#define KK 8

#define PAD(i) ((i) + ((i) >> 5))
// After dft16, X[k0+4*k1] sits at slot 4*k0+k1 (k0=r&3, k1=r>>2)
#define PERM16(r) ((((r) & 3) << 2) | ((r) >> 2))

// fp64-accurate trig tables in global ws: half table for 2pi*j/4096 (j<2048,
// sign-fold for j>=2048) + full 256-entry table for iter-1 twiddles.
__global__ void build_table_k(float* __restrict__ ct, float* __restrict__ st,
                              float* __restrict__ tc, float* __restrict__ ts) {
    int j = blockIdx.x * blockDim.x + threadIdx.x;
    if (j < 2048) {
        double th = (double)j * (6.283185307179586476925287 / 4096.0);
        ct[j] = (float)cos(th);
        st[j] = (float)sin(th);
    }
    if (j < 256) {
        double th = (double)j * (6.283185307179586476925287 / 256.0);
        tc[j] = (float)cos(th);
        ts[j] = (float)sin(th);
    }
}

// forward 4-point DFT (w4 = -i), in place
__device__ __forceinline__ void dft4(float& r0, float& i0, float& r1, float& i1,
                                     float& r2, float& i2, float& r3, float& i3) {
    float t0r = r0 + r2, t0i = i0 + i2;
    float t1r = r0 - r2, t1i = i0 - i2;
    float t2r = r1 + r3, t2i = i1 + i3;
    float t3r = r1 - r3, t3i = i1 - i3;
    r0 = t0r + t2r; i0 = t0i + t2i;
    r2 = t0r - t2r; i2 = t0i - t2i;
    r1 = t1r + t3i; i1 = t1i - t3r;   // y1 = t1 - i*t3
    r3 = t1r - t3i; i3 = t1i + t3r;   // y3 = t1 + i*t3
}

// multiply (xr + i*xi) by (c - i*s)
__device__ __forceinline__ void cmulw(float& xr, float& xi, float c, float s) {
    float r = xr * c + xi * s;
    float i = xi * c - xr * s;
    xr = r; xi = i;
}

// forward 16-point DFT in registers; output permuted per PERM16
__device__ __forceinline__ void dft16(float* vr, float* vi) {
#pragma unroll
    for (int n0 = 0; n0 < 4; ++n0)
        dft4(vr[n0], vi[n0], vr[n0 + 4], vi[n0 + 4],
             vr[n0 + 8], vi[n0 + 8], vr[n0 + 12], vi[n0 + 12]);
    // slot n0 + 4*k0 holds G_{n0}[k0]; apply w16^{n0*k0}
    const float C1 = 0.92387953251128674f, S1 = 0.38268343236508978f;
    const float C2 = 0.70710678118654752f;
    cmulw(vr[5],  vi[5],  C1,  S1);    // m=1
    cmulw(vr[9],  vi[9],  C2,  C2);    // m=2
    cmulw(vr[13], vi[13], S1,  C1);    // m=3
    cmulw(vr[6],  vi[6],  C2,  C2);    // m=2
    cmulw(vr[10], vi[10], 0.f, 1.f);   // m=4 (mult by -i)
    cmulw(vr[14], vi[14], -C2, C2);    // m=6
    cmulw(vr[7],  vi[7],  S1,  C1);    // m=3
    cmulw(vr[11], vi[11], -C2, C2);    // m=6
    cmulw(vr[15], vi[15], -C1, -S1);   // m=9
#pragma unroll
    for (int k0 = 0; k0 < 4; ++k0)
        dft4(vr[4 * k0], vi[4 * k0], vr[4 * k0 + 1], vi[4 * k0 + 1],
             vr[4 * k0 + 2], vi[4 * k0 + 2], vr[4 * k0 + 3], vi[4 * k0 + 3]);
}

// One block per (b,c) row: gain, Stockham radix-16 FFT (3 passes), register
// top-8, sparse inverse (8 sinusoids).
__global__ __launch_bounds__(THREADS)
void fft_topk_k(const float* __restrict__ x, const float* __restrict__ te,
                const float* __restrict__ W, const float* __restrict__ bias,
                const float* __restrict__ gct, const float* __restrict__ gst,
                const float* __restrict__ gtc, const float* __restrict__ gts,
                float* __restrict__ out) {
    __shared__ float re[4224], im[4224];      // PAD(4095)=4222
    __shared__ float ct[2048], st[2048];
    __shared__ float t16c[256], t16s[256];
    __shared__ float wv[4];
    __shared__ int   wi[4];
    __shared__ int   bcastF;
    __shared__ float selA[KK], selB[KK];
    __shared__ int   selF[KK];

    int j = threadIdx.x;
    int row = blockIdx.x;
    int b = row >> 7, c = row & 127;

    // stage trig tables (coalesced; consumed after first __syncthreads)
    for (int i = j; i < 2048; i += THREADS) { ct[i] = gct[i]; st[i] = gst[i]; }
    t16c[j] = gtc[j]; t16s[j] = gts[j];

    // fused modulation scale: dot(te[b], W[c]) (512 terms, 2/thread)
    float ps = te[b * 512 + j] * W[c * 512 + j]
             + te[b * 512 + 256 + j] * W[c * 512 + 256 + j];
#pragma unroll
    for (int off = 32; off; off >>= 1) ps += __shfl_down(ps, off);
    if ((j & 63) == 0) wv[j >> 6] = ps;
    __syncthreads();
    float gm = 1.0f + tanhf(wv[0] + wv[1] + wv[2] + wv[3] + bias[c]);

    const float* xp = x + (size_t)row * LL;
    float vr[16], vi[16];

    // ---- Stockham iter 0 (Ns=1): read global, DFT16, write LDS ----
#pragma unroll
    for (int r = 0; r < 16; ++r) { vr[r] = xp[j + 256 * r] * gm; vi[r] = 0.f; }
    dft16(vr, vi);
    __syncthreads();   // also covers table staging + wv reuse below
#pragma unroll
    for (int r = 0; r < 16; ++r) {
        int d = PAD(j * 16 + r);
        re[d] = vr[PERM16(r)]; im[d] = vi[PERM16(r)];
    }
    __syncthreads();

    // ---- iter 1 (Ns=16) ----
#pragma unroll
    for (int r = 0; r < 16; ++r) {
        int a = PAD(j + 256 * r);
        vr[r] = re[a]; vi[r] = im[a];
    }
    {
        int a16 = j & 15;
#pragma unroll
        for (int r = 1; r < 16; ++r) {
            int m = a16 * r;                       // < 256
            cmulw(vr[r], vi[r], t16c[m], t16s[m]);
        }
    }
    dft16(vr, vi);
    __syncthreads();
    {
        int base = ((j >> 4) << 8) + (j & 15);
#pragma unroll
        for (int r = 0; r < 16; ++r) {
            int d = PAD(base + 16 * r);
            re[d] = vr[PERM16(r)]; im[d] = vi[PERM16(r)];
        }
    }
    __syncthreads();

    // ---- iter 2 (Ns=256): output stays in registers; X[j+256r]=v[PERM16(r)] ----
#pragma unroll
    for (int r = 0; r < 16; ++r) {
        int a = PAD(j + 256 * r);
        vr[r] = re[a]; vi[r] = im[a];
    }
#pragma unroll
    for (int r = 1; r < 16; ++r) {
        int m = j * r;                             // <= 3825
        float sgn = (m & 2048) ? -1.f : 1.f;
        int mm = m & 2047;
        cmulw(vr[r], vi[r], ct[mm] * sgn, st[mm] * sgn);
    }
    dft16(vr, vi);

    // ---- register top-8 over bins 0..2048 ----
    float amp[16];
#pragma unroll
    for (int r = 0; r < 16; ++r) {
        int f = j + 256 * r;
        float rr = vr[PERM16(r)], ii = vi[PERM16(r)];
        float a2 = rr * rr + ii * ii;
        amp[r] = (f <= 2048) ? a2 : -1.f;
    }
    for (int it = 0; it < KK; ++it) {
        float bv = -1.f; int br = 0;
#pragma unroll
        for (int r = 0; r < 16; ++r)               // ascending r => lower f wins ties
            if (amp[r] > bv) { bv = amp[r]; br = r; }
        int bf = j + 256 * br;
#pragma unroll
        for (int off = 32; off; off >>= 1) {
            float ov = __shfl_down(bv, off);
            int   of = __shfl_down(bf, off);
            if (ov > bv || (ov == bv && of < bf)) { bv = ov; bf = of; }
        }
        if ((j & 63) == 0) { wv[j >> 6] = bv; wi[j >> 6] = bf; }
        __syncthreads();
        if (j == 0) {
#pragma unroll
            for (int w = 1; w < 4; ++w)
                if (wv[w] > bv || (wv[w] == bv && wi[w] < bf)) { bv = wv[w]; bf = wi[w]; }
            bcastF = bf;
        }
        __syncthreads();
        int f = bcastF;
        if ((f & 255) == j) {                      // owner thread records & removes
            int r = f >> 8;
            amp[r] = -1.f;
            bool edge = (f == 0) || (f == 2048);
            float wgt = edge ? 1.f : 2.f;
            const float inv = 1.0f / (float)LL;
            selF[it] = f;
            selA[it] = wgt * inv * vr[PERM16(r)];
            selB[it] = edge ? 0.f : wgt * inv * vi[PERM16(r)];  // c2r ignores
                                                               // imag at DC/Nyq
        }
        __syncthreads();
    }

    // ---- sparse inverse: out[n] = sum_k A_k cos(2pi f_k n/L) - B_k sin(...) ----
    float sa[KK], sb[KK]; int sf[KK];
#pragma unroll
    for (int k = 0; k < KK; ++k) { sa[k] = selA[k]; sb[k] = selB[k]; sf[k] = selF[k]; }

    float* op = out + (size_t)row * LL;
#pragma unroll 1
    for (int q = 0; q < 16; ++q) {
        int i = j + 256 * q;
        float acc = 0.f;
#pragma unroll
        for (int k = 0; k < KK; ++k) {
            int m = (sf[k] * i) & (LL - 1);        // exact integer range reduction
            float sgn = (m & 2048) ? -1.f : 1.f;
            int mm = m & 2047;
            acc = fmaf(sa[k] * sgn, ct[mm], acc);
            acc = fmaf(-sb[k] * sgn, st[mm], acc);
        }
        op[i] = acc;
    }
}

extern "C" void kernel_launch(void* const* d_in, const int* in_sizes, int n_in,
                              void* d_out, int out_size, void* d_ws, size_t ws_size,
                              hipStream_t stream) {
    const float* x    = (const float*)d_in[0];
    const float* te   = (const float*)d_in[1];
    const float* W    = (const float*)d_in[2];
    const float* bias = (const float*)d_in[3];
    float* out = (float*)d_out;

    float* ct = (float*)d_ws;                        // 2048 f = 8 KB
    float* st = (float*)((char*)d_ws + 8192);        // 8 KB
    float* tc = (float*)((char*)d_ws + 16384);       // 1 KB
    float* ts = (float*)((char*)d_ws + 17408);       // 1 KB

    build_table_k<<<8, 256, 0, stream>>>(ct, st, tc, ts);
    fft_topk_k<<<32 * 128, THREADS, 0, stream>>>(x, te, W, bias, ct, st, tc, ts, out);
}

// Round 3
// 84.004 us; speedup vs baseline: 3.5173x; 1.7711x over previous
//
#include <hip/hip_runtime.h>

#define LL 4096
#define THREADS 256
#define KK 8

#define PAD(i) ((i) + ((i) >> 5))
// After dft16, X[k0+4*k1] sits at slot 4*k0+k1 (k0=r&3, k1=r>>2)
#define PERM16(r) ((((r) & 3) << 2) | ((r) >> 2))

// HW trig, input in REVOLUTIONS: sinr(x) = sin(2*pi*x). Args here are exact
// m/4096 or m/256, so no range-reduction error.
__device__ __forceinline__ float sinr(float x) {
    float r; asm("v_sin_f32 %0, %1" : "=v"(r) : "v"(x)); return r;
}
__device__ __forceinline__ float cosr(float x) {
    float r; asm("v_cos_f32 %0, %1" : "=v"(r) : "v"(x)); return r;
}

// forward 4-point DFT (w4 = -i), in place
__device__ __forceinline__ void dft4(float& r0, float& i0, float& r1, float& i1,
                                     float& r2, float& i2, float& r3, float& i3) {
    float t0r = r0 + r2, t0i = i0 + i2;
    float t1r = r0 - r2, t1i = i0 - i2;
    float t2r = r1 + r3, t2i = i1 + i3;
    float t3r = r1 - r3, t3i = i1 - i3;
    r0 = t0r + t2r; i0 = t0i + t2i;
    r2 = t0r - t2r; i2 = t0i - t2i;
    r1 = t1r + t3i; i1 = t1i - t3r;   // y1 = t1 - i*t3
    r3 = t1r - t3i; i3 = t1i + t3r;   // y3 = t1 + i*t3
}

// multiply (xr + i*xi) by (c - i*s)
__device__ __forceinline__ void cmulw(float& xr, float& xi, float c, float s) {
    float r = xr * c + xi * s;
    float i = xi * c - xr * s;
    xr = r; xi = i;
}

// forward 16-point DFT in registers; output permuted per PERM16
__device__ __forceinline__ void dft16(float* vr, float* vi) {
#pragma unroll
    for (int n0 = 0; n0 < 4; ++n0)
        dft4(vr[n0], vi[n0], vr[n0 + 4], vi[n0 + 4],
             vr[n0 + 8], vi[n0 + 8], vr[n0 + 12], vi[n0 + 12]);
    const float C1 = 0.92387953251128674f, S1 = 0.38268343236508978f;
    const float C2 = 0.70710678118654752f;
    cmulw(vr[5],  vi[5],  C1,  S1);    // m=1
    cmulw(vr[9],  vi[9],  C2,  C2);    // m=2
    cmulw(vr[13], vi[13], S1,  C1);    // m=3
    cmulw(vr[6],  vi[6],  C2,  C2);    // m=2
    cmulw(vr[10], vi[10], 0.f, 1.f);   // m=4 (mult by -i)
    cmulw(vr[14], vi[14], -C2, C2);    // m=6
    cmulw(vr[7],  vi[7],  S1,  C1);    // m=3
    cmulw(vr[11], vi[11], -C2, C2);    // m=6
    cmulw(vr[15], vi[15], -C1, -S1);   // m=9
#pragma unroll
    for (int k0 = 0; k0 < 4; ++k0)
        dft4(vr[4 * k0], vi[4 * k0], vr[4 * k0 + 1], vi[4 * k0 + 1],
             vr[4 * k0 + 2], vi[4 * k0 + 2], vr[4 * k0 + 3], vi[4 * k0 + 3]);
}

__global__ __launch_bounds__(THREADS, 4)
void fft_topk_k(const float* __restrict__ x, const float* __restrict__ te,
                const float* __restrict__ W, const float* __restrict__ bias,
                float* __restrict__ out) {
    __shared__ float re[4224], im[4224];   // PAD(4095)=4222
    __shared__ float wv[8];                // double-buffered cross-wave slots
    __shared__ int   wi[8];
    __shared__ float selA[KK], selB[KK];
    __shared__ int   selF[KK];

    int j = threadIdx.x;
    int row = blockIdx.x;
    int b = row >> 7, c = row & 127;

    // fused modulation: dot(te[b], W[c]) (512 terms, 2/thread)
    float ps = te[b * 512 + j] * W[c * 512 + j]
             + te[b * 512 + 256 + j] * W[c * 512 + 256 + j];
#pragma unroll
    for (int off = 32; off; off >>= 1) ps += __shfl_down(ps, off);
    if ((j & 63) == 0) wv[j >> 6] = ps;

    const float* xp = x + (size_t)row * LL;
    float vr[16], vi[16];
    // issue global loads before the sync (independent of wv)
#pragma unroll
    for (int r = 0; r < 16; ++r) { vr[r] = xp[j + 256 * r]; vi[r] = 0.f; }
    __syncthreads();
    float gm = 1.0f + tanhf(wv[0] + wv[1] + wv[2] + wv[3] + bias[c]);

    // ---- Stockham iter 0 (Ns=1) ----
#pragma unroll
    for (int r = 0; r < 16; ++r) vr[r] *= gm;
    dft16(vr, vi);
#pragma unroll
    for (int r = 0; r < 16; ++r) {
        int d = PAD(j * 16 + r);
        re[d] = vr[PERM16(r)]; im[d] = vi[PERM16(r)];
    }
    __syncthreads();

    // ---- iter 1 (Ns=16) ----
#pragma unroll
    for (int r = 0; r < 16; ++r) {
        int a = PAD(j + 256 * r);
        vr[r] = re[a]; vi[r] = im[a];
    }
    {
        int a16 = j & 15;
        const float i256 = 1.0f / 256.0f;
#pragma unroll
        for (int r = 1; r < 16; ++r) {
            float v = (float)(a16 * r) * i256;     // exact
            cmulw(vr[r], vi[r], cosr(v), sinr(v));
        }
    }
    dft16(vr, vi);
    __syncthreads();
    {
        int base = ((j >> 4) << 8) + (j & 15);
#pragma unroll
        for (int r = 0; r < 16; ++r) {
            int d = PAD(base + 16 * r);
            re[d] = vr[PERM16(r)]; im[d] = vi[PERM16(r)];
        }
    }
    __syncthreads();

    // ---- iter 2 (Ns=256): output stays in registers; X[j+256r]=v[PERM16(r)] ----
#pragma unroll
    for (int r = 0; r < 16; ++r) {
        int a = PAD(j + 256 * r);
        vr[r] = re[a]; vi[r] = im[a];
    }
    {
        const float i4096 = 1.0f / 4096.0f;
#pragma unroll
        for (int r = 1; r < 16; ++r) {
            float v = (float)(j * r) * i4096;      // j*r <= 3825, exact
            cmulw(vr[r], vi[r], cosr(v), sinr(v));
        }
    }
    dft16(vr, vi);

    // ---- register top-8 over bins 0..2048 ----
    float amp[16];
#pragma unroll
    for (int r = 0; r < 16; ++r) {
        int f = j + 256 * r;
        float rr = vr[PERM16(r)], ii = vi[PERM16(r)];
        float a2 = rr * rr + ii * ii;
        amp[r] = (f <= 2048) ? a2 : -1.f;
    }
    float lv = -1.f; int lr = 0;
#pragma unroll
    for (int r = 0; r < 16; ++r)
        if (amp[r] > lv) { lv = amp[r]; lr = r; }   // ascending r: lower f on tie

    for (int it = 0; it < KK; ++it) {
        float bv = lv; int bf = j + (lr << 8);
#pragma unroll
        for (int off = 32; off; off >>= 1) {
            float ov = __shfl_down(bv, off);
            int   of = __shfl_down(bf, off);
            if (ov > bv || (ov == bv && of < bf)) { bv = ov; bf = of; }
        }
        int p = (it & 1) << 2;                      // double-buffer slot
        if ((j & 63) == 0) { wv[p + (j >> 6)] = bv; wi[p + (j >> 6)] = bf; }
        __syncthreads();
        float cv = wv[p]; int cf = wi[p];
#pragma unroll
        for (int w = 1; w < 4; ++w)
            if (wv[p + w] > cv || (wv[p + w] == cv && wi[p + w] < cf)) {
                cv = wv[p + w]; cf = wi[p + w];
            }
        if ((cf & 255) == j) {                      // unique owner records & removes
            int r = cf >> 8;
            float rr = 0.f, ii = 0.f;
#pragma unroll
            for (int r2 = 0; r2 < 16; ++r2)         // static-index selects (no scratch)
                if (r2 == r) { rr = vr[PERM16(r2)]; ii = vi[PERM16(r2)]; amp[r2] = -1.f; }
            bool edge = (cf == 0) || (cf == 2048);
            float wgt = edge ? 1.f : 2.f;
            const float inv = 1.0f / (float)LL;
            selF[it] = cf;
            selA[it] = wgt * inv * rr;
            selB[it] = edge ? 0.f : wgt * inv * ii;  // c2r ignores imag at DC/Nyq
            lv = -1.f; lr = 0;
#pragma unroll
            for (int r2 = 0; r2 < 16; ++r2)
                if (amp[r2] > lv) { lv = amp[r2]; lr = r2; }
        }
    }
    __syncthreads();

    // ---- sparse inverse via 8 register rotators ----
    // w_k = (A_k + i B_k) e^{i 2pi f_k n / L}; out[n] = sum Re(w_k)
    float wr_[KK], wi_[KK], cS[KK], sS[KK];
    const float i4096 = 1.0f / 4096.0f;
#pragma unroll
    for (int k = 0; k < KK; ++k) {
        int f = selF[k];
        float A = selA[k], Bv = selB[k];
        int m0 = (f * j) & 4095;
        float c0 = cosr((float)m0 * i4096), s0 = sinr((float)m0 * i4096);
        wr_[k] = A * c0 - Bv * s0;
        wi_[k] = A * s0 + Bv * c0;
        int ms = (f << 8) & 4095;                  // step: 256 samples
        cS[k] = cosr((float)ms * i4096);
        sS[k] = sinr((float)ms * i4096);
    }
    float* op = out + (size_t)row * LL;
#pragma unroll 1
    for (int q = 0; q < 16; ++q) {
        float acc = 0.f;
#pragma unroll
        for (int k = 0; k < KK; ++k) {
            acc += wr_[k];
            float nc = wr_[k] * cS[k] - wi_[k] * sS[k];
            float ni = wi_[k] * cS[k] + wr_[k] * sS[k];
            wr_[k] = nc; wi_[k] = ni;
        }
        op[j + (q << 8)] = acc;
    }
}

extern "C" void kernel_launch(void* const* d_in, const int* in_sizes, int n_in,
                              void* d_out, int out_size, void* d_ws, size_t ws_size,
                              hipStream_t stream) {
    const float* x    = (const float*)d_in[0];
    const float* te   = (const float*)d_in[1];
    const float* W    = (const float*)d_in[2];
    const float* bias = (const float*)d_in[3];
    float* out = (float*)d_out;
    fft_topk_k<<<32 * 128, THREADS, 0, stream>>>(x, te, W, bias, out);
}

// Round 4
// 69.173 us; speedup vs baseline: 4.2714x; 1.2144x over previous
//
#include <hip/hip_runtime.h>

#define LL 4096
#define THREADS 256
#define KK 8

// XOR swizzle: all FFT LDS patterns (stride-16 write, stride-1 read,
// grouped write, mirrored read) become <=2-way (free) with zero padding.
#define SW(i) ((i) ^ (((i) >> 5) & 31))
// After dft16, X[k0+4*k1] sits at slot 4*k0+k1 (k0=r&3, k1=r>>2)
#define PERM16(r) ((((r) & 3) << 2) | ((r) >> 2))

// HW trig, input in REVOLUTIONS: sinr(x)=sin(2*pi*x). All args here are exact
// m/4096 in [0,1), so no range-reduction error.
__device__ __forceinline__ float sinr(float x) {
    float r; asm("v_sin_f32 %0, %1" : "=v"(r) : "v"(x)); return r;
}
__device__ __forceinline__ float cosr(float x) {
    float r; asm("v_cos_f32 %0, %1" : "=v"(r) : "v"(x)); return r;
}

// forward 4-point DFT (w4 = -i), in place
__device__ __forceinline__ void dft4(float& r0, float& i0, float& r1, float& i1,
                                     float& r2, float& i2, float& r3, float& i3) {
    float t0r = r0 + r2, t0i = i0 + i2;
    float t1r = r0 - r2, t1i = i0 - i2;
    float t2r = r1 + r3, t2i = i1 + i3;
    float t3r = r1 - r3, t3i = i1 - i3;
    r0 = t0r + t2r; i0 = t0i + t2i;
    r2 = t0r - t2r; i2 = t0i - t2i;
    r1 = t1r + t3i; i1 = t1i - t3r;   // y1 = t1 - i*t3
    r3 = t1r - t3i; i3 = t1i + t3r;   // y3 = t1 + i*t3
}

// multiply (xr + i*xi) by (c - i*s)
__device__ __forceinline__ void cmulw(float& xr, float& xi, float c, float s) {
    float r = xr * c + xi * s;
    float i = xi * c - xr * s;
    xr = r; xi = i;
}

// forward 16-point DFT in registers; output permuted per PERM16
__device__ __forceinline__ void dft16(float* vr, float* vi) {
#pragma unroll
    for (int n0 = 0; n0 < 4; ++n0)
        dft4(vr[n0], vi[n0], vr[n0 + 4], vi[n0 + 4],
             vr[n0 + 8], vi[n0 + 8], vr[n0 + 12], vi[n0 + 12]);
    const float C1 = 0.92387953251128674f, S1 = 0.38268343236508978f;
    const float C2 = 0.70710678118654752f;
    cmulw(vr[5],  vi[5],  C1,  S1);    // m=1
    cmulw(vr[9],  vi[9],  C2,  C2);    // m=2
    cmulw(vr[13], vi[13], S1,  C1);    // m=3
    cmulw(vr[6],  vi[6],  C2,  C2);    // m=2
    cmulw(vr[10], vi[10], 0.f, 1.f);   // m=4 (mult by -i)
    cmulw(vr[14], vi[14], -C2, C2);    // m=6
    cmulw(vr[7],  vi[7],  S1,  C1);    // m=3
    cmulw(vr[11], vi[11], -C2, C2);    // m=6
    cmulw(vr[15], vi[15], -C1, -S1);   // m=9
#pragma unroll
    for (int k0 = 0; k0 < 4; ++k0)
        dft4(vr[4 * k0], vi[4 * k0], vr[4 * k0 + 1], vi[4 * k0 + 1],
             vr[4 * k0 + 2], vi[4 * k0 + 2], vr[4 * k0 + 3], vi[4 * k0 + 3]);
}

// Sequential top-8 extraction for one row (block-wide, tie -> lower bin).
#define TOPK_ROW(AMP, AN, XR, XI, XNR, SF, SA, SB)                              \
  {                                                                             \
    float lv = -1.f; int lr = 0;                                                \
    _Pragma("unroll")                                                           \
    for (int r = 0; r < 8; ++r) if (AMP[r] > lv) { lv = AMP[r]; lr = r; }       \
    if (AN > lv) { lv = AN; lr = 8; }                                           \
    for (int it = 0; it < KK; ++it) {                                           \
      float bv = lv; int bf = t + (lr << 8);                                    \
      _Pragma("unroll")                                                         \
      for (int off = 32; off; off >>= 1) {                                      \
        float ov = __shfl_down(bv, off);                                        \
        int   of = __shfl_down(bf, off);                                        \
        if (ov > bv || (ov == bv && of < bf)) { bv = ov; bf = of; }             \
      }                                                                         \
      int p = (it & 1) << 2;                                                    \
      if ((t & 63) == 0) { wv[p + (t >> 6)] = bv; wi[p + (t >> 6)] = bf; }      \
      __syncthreads();                                                          \
      float cv = wv[p]; int cf = wi[p];                                         \
      _Pragma("unroll")                                                         \
      for (int w = 1; w < 4; ++w)                                               \
        if (wv[p + w] > cv || (wv[p + w] == cv && wi[p + w] < cf)) {            \
          cv = wv[p + w]; cf = wi[p + w]; }                                     \
      if ((cf & 255) == t) {                                                    \
        int r = cf >> 8;                                                        \
        float rr = 0.f, ii = 0.f;                                               \
        _Pragma("unroll")                                                       \
        for (int r2 = 0; r2 < 8; ++r2)                                          \
          if (r2 == r) { rr = XR[r2]; ii = XI[r2]; AMP[r2] = -1.f; }            \
        if (r == 8) { rr = XNR; ii = 0.f; AN = -1.f; }                          \
        bool edge = (cf == 0) || (cf == 2048);                                  \
        float wgt = edge ? 1.f : 2.f;                                           \
        SF[it] = cf;                                                            \
        SA[it] = wgt * (1.0f / 4096.0f) * rr;                                   \
        SB[it] = edge ? 0.f : wgt * (1.0f / 4096.0f) * ii;                      \
        lv = -1.f; lr = 0;                                                      \
        _Pragma("unroll")                                                       \
        for (int r2 = 0; r2 < 8; ++r2)                                          \
          if (AMP[r2] > lv) { lv = AMP[r2]; lr = r2; }                          \
        if (AN > lv) { lv = AN; lr = 8; }                                       \
      }                                                                         \
    }                                                                           \
  }

// Sparse inverse for one row via 8 register rotators; half-period symmetry:
// out[n+2048] = sum_k (-1)^{f_k} Re(w_k[n])  -> only 8 rotation steps.
#define INV_ROW(SF, SA, SB, OP)                                                 \
  {                                                                             \
    float wr_[KK], wj_[KK], cS[KK], sS[KK], sg[KK];                             \
    const float i4096 = 1.0f / 4096.0f;                                         \
    _Pragma("unroll")                                                           \
    for (int k = 0; k < KK; ++k) {                                              \
      int f = SF[k]; float A = SA[k], Bv = SB[k];                               \
      int m0 = (f * t) & 4095;                                                  \
      float c0 = cosr((float)m0 * i4096), s0 = sinr((float)m0 * i4096);         \
      wr_[k] = A * c0 - Bv * s0;                                                \
      wj_[k] = A * s0 + Bv * c0;                                                \
      int ms = (f & 15) << 8;                                                   \
      cS[k] = cosr((float)ms * i4096); sS[k] = sinr((float)ms * i4096);         \
      sg[k] = (f & 1) ? -1.f : 1.f;                                             \
    }                                                                           \
    _Pragma("unroll 1")                                                         \
    for (int q = 0; q < 8; ++q) {                                               \
      float acc = 0.f, acd = 0.f;                                               \
      _Pragma("unroll")                                                         \
      for (int k = 0; k < KK; ++k) {                                            \
        acc += wr_[k];                                                          \
        acd = fmaf(sg[k], wr_[k], acd);                                         \
        float nc = wr_[k] * cS[k] - wj_[k] * sS[k];                             \
        float ni = wj_[k] * cS[k] + wr_[k] * sS[k];                             \
        wr_[k] = nc; wj_[k] = ni;                                               \
      }                                                                         \
      OP[t + (q << 8)] = acc;                                                   \
      OP[t + (q << 8) + 2048] = acd;                                            \
    }                                                                           \
  }

// One block per ROW PAIR: z = g0*x0 + i*g1*x1, one 4096-pt complex FFT,
// untangle -> two real spectra, top-8 each, sparse inverse each.
__global__ __launch_bounds__(THREADS, 4)
void fft2_topk_k(const float* __restrict__ x, const float* __restrict__ te,
                 const float* __restrict__ W, const float* __restrict__ bias,
                 float* __restrict__ out) {
    __shared__ float re[LL], im[LL];
    __shared__ float wv[8];
    __shared__ int   wi[8];
    __shared__ float selA0[KK], selB0[KK], selA1[KK], selB1[KK];
    __shared__ int   selF0[KK], selF1[KK];

    int t = threadIdx.x;
    int pair = blockIdx.x;
    int b = pair >> 6;
    int c0 = (pair & 63) << 1, c1 = c0 + 1;
    int row0 = (b << 7) + c0, row1 = row0 + 1;

    // two modulation dots: waves 0-1 -> row0, waves 2-3 -> row1
    {
        int half = t >> 7, tt = t & 127;
        const float* tp = te + b * 512;
        const float* wp = W + (half ? c1 : c0) * 512;
        float ps = tp[tt] * wp[tt] + tp[tt + 128] * wp[tt + 128]
                 + tp[tt + 256] * wp[tt + 256] + tp[tt + 384] * wp[tt + 384];
#pragma unroll
        for (int off = 32; off; off >>= 1) ps += __shfl_down(ps, off);
        if ((t & 63) == 0) wv[t >> 6] = ps;
    }

    const float* xp0 = x + (size_t)row0 * LL;
    const float* xp1 = x + (size_t)row1 * LL;
    float vr[16], vi[16];
#pragma unroll
    for (int r = 0; r < 16; ++r) { vr[r] = xp0[t + 256 * r]; vi[r] = xp1[t + 256 * r]; }
    __syncthreads();
    float g0 = 1.0f + tanhf(wv[0] + wv[1] + bias[c0]);
    float g1 = 1.0f + tanhf(wv[2] + wv[3] + bias[c1]);
#pragma unroll
    for (int r = 0; r < 16; ++r) { vr[r] *= g0; vi[r] *= g1; }

    // ---- Stockham iter 0 (Ns=1) ----
    dft16(vr, vi);
#pragma unroll
    for (int r = 0; r < 16; ++r) {
        int d = SW(t * 16 + r);
        re[d] = vr[PERM16(r)]; im[d] = vi[PERM16(r)];
    }
    __syncthreads();

    // ---- iter 1 (Ns=16) ----
#pragma unroll
    for (int r = 0; r < 16; ++r) {
        int a = SW(t + 256 * r);
        vr[r] = re[a]; vi[r] = im[a];
    }
    {
        int a16 = t & 15;
        const float i256 = 1.0f / 256.0f;
#pragma unroll
        for (int r = 1; r < 16; ++r) {
            float v = (float)(a16 * r) * i256;     // exact
            cmulw(vr[r], vi[r], cosr(v), sinr(v));
        }
    }
    dft16(vr, vi);
    __syncthreads();
    {
        int base = ((t >> 4) << 8) + (t & 15);
#pragma unroll
        for (int r = 0; r < 16; ++r) {
            int d = SW(base + 16 * r);
            re[d] = vr[PERM16(r)]; im[d] = vi[PERM16(r)];
        }
    }
    __syncthreads();

    // ---- iter 2 (Ns=256): Z[t+256r] = v[PERM16(r)] ----
#pragma unroll
    for (int r = 0; r < 16; ++r) {
        int a = SW(t + 256 * r);
        vr[r] = re[a]; vi[r] = im[a];
    }
    {
        const float i4096 = 1.0f / 4096.0f;
#pragma unroll
        for (int r = 1; r < 16; ++r) {
            float v = (float)(t * r) * i4096;      // t*r <= 3825, exact
            cmulw(vr[r], vi[r], cosr(v), sinr(v));
        }
    }
    dft16(vr, vi);
    __syncthreads();                               // iter-1 data fully consumed

    // write Z back for the untangle exchange
#pragma unroll
    for (int r = 0; r < 16; ++r) {
        int d = SW(t + 256 * r);
        re[d] = vr[PERM16(r)]; im[d] = vi[PERM16(r)];
    }
    __syncthreads();

    // ---- untangle: X1=(Z[k]+conj(Z[-k]))/2, X2=-i(Z[k]-conj(Z[-k]))/2 ----
    float x1r[8], x1i[8], x2r[8], x2i[8], amp1[8], amp2[8];
#pragma unroll
    for (int r = 0; r < 8; ++r) {
        int k = t + 256 * r;                       // 0..2047
        int a1 = SW(k), a2 = SW((4096 - k) & 4095);
        float zr = re[a1], zi = im[a1];
        float yr = re[a2], yi = im[a2];
        x1r[r] = 0.5f * (zr + yr);
        x1i[r] = 0.5f * (zi - yi);
        x2r[r] = 0.5f * (zi + yi);
        x2i[r] = 0.5f * (yr - zr);
        amp1[r] = x1r[r] * x1r[r] + x1i[r] * x1i[r];
        amp2[r] = x2r[r] * x2r[r] + x2i[r] * x2i[r];
    }
    // Nyquist bin 2048 (real): thread 0's 9th slot
    float xn1 = 0.f, xn2 = 0.f, an1 = -1.f, an2 = -1.f;
    if (t == 0) {
        int a = SW(2048);
        xn1 = re[a]; xn2 = im[a];
        an1 = xn1 * xn1; an2 = xn2 * xn2;
    }

    TOPK_ROW(amp1, an1, x1r, x1i, xn1, selF0, selA0, selB0);
    TOPK_ROW(amp2, an2, x2r, x2i, xn2, selF1, selA1, selB1);
    __syncthreads();

    float* op0 = out + (size_t)row0 * LL;
    float* op1 = out + (size_t)row1 * LL;
    INV_ROW(selF0, selA0, selB0, op0);
    INV_ROW(selF1, selA1, selB1, op1);
}

extern "C" void kernel_launch(void* const* d_in, const int* in_sizes, int n_in,
                              void* d_out, int out_size, void* d_ws, size_t ws_size,
                              hipStream_t stream) {
    const float* x    = (const float*)d_in[0];
    const float* te   = (const float*)d_in[1];
    const float* W    = (const float*)d_in[2];
    const float* bias = (const float*)d_in[3];
    float* out = (float*)d_out;
    fft2_topk_k<<<2048, THREADS, 0, stream>>>(x, te, W, bias, out);
}

// Round 5
// 63.851 us; speedup vs baseline: 4.6275x; 1.0834x over previous
//
#include <hip/hip_runtime.h>

#define LL 4096
#define THREADS 512
#define KK 8

// XOR swizzle: FFT LDS patterns become <=2-way (free) with zero padding.
#define SW(i) ((i) ^ (((i) >> 5) & 31))
// dft8: X[k0+4*k1] sits in slot 2*k0+k1 -> slot holding X[r]:
#define PERM8(r) ((((r) & 3) << 1) | ((r) >> 2))

// HW trig, input in REVOLUTIONS: sinr(x)=sin(2*pi*x). All args are exact
// m/2^k in [0,1), so no range-reduction error.
__device__ __forceinline__ float sinr(float x) {
    float r; asm("v_sin_f32 %0, %1" : "=v"(r) : "v"(x)); return r;
}
__device__ __forceinline__ float cosr(float x) {
    float r; asm("v_cos_f32 %0, %1" : "=v"(r) : "v"(x)); return r;
}

// forward 4-point DFT (w4 = -i), in place
__device__ __forceinline__ void dft4(float& r0, float& i0, float& r1, float& i1,
                                     float& r2, float& i2, float& r3, float& i3) {
    float t0r = r0 + r2, t0i = i0 + i2;
    float t1r = r0 - r2, t1i = i0 - i2;
    float t2r = r1 + r3, t2i = i1 + i3;
    float t3r = r1 - r3, t3i = i1 - i3;
    r0 = t0r + t2r; i0 = t0i + t2i;
    r2 = t0r - t2r; i2 = t0i - t2i;
    r1 = t1r + t3i; i1 = t1i - t3r;   // y1 = t1 - i*t3
    r3 = t1r - t3i; i3 = t1i + t3r;   // y3 = t1 + i*t3
}

// multiply (xr + i*xi) by (c - i*s)
__device__ __forceinline__ void cmulw(float& xr, float& xi, float c, float s) {
    float r = xr * c + xi * s;
    float i = xi * c - xr * s;
    xr = r; xi = i;
}

// forward 8-point DFT; output permuted per PERM8 (verified: X[k]=w8^k for e_1)
__device__ __forceinline__ void dft8(float* vr, float* vi) {
    dft4(vr[0], vi[0], vr[2], vi[2], vr[4], vi[4], vr[6], vi[6]);   // n0=0 group
    dft4(vr[1], vi[1], vr[3], vi[3], vr[5], vi[5], vr[7], vi[7]);   // n0=1 group
    const float C2 = 0.70710678118654752f;
    cmulw(vr[3], vi[3],  C2, C2);    // w8^1
    cmulw(vr[5], vi[5], 0.f, 1.f);   // w8^2 = -i
    cmulw(vr[7], vi[7], -C2, C2);    // w8^3
#pragma unroll
    for (int k0 = 0; k0 < 4; ++k0) {
        float ar = vr[2 * k0], ai = vi[2 * k0];
        float br = vr[2 * k0 + 1], bi = vi[2 * k0 + 1];
        vr[2 * k0]     = ar + br; vi[2 * k0]     = ai + bi;   // X[k0]
        vr[2 * k0 + 1] = ar - br; vi[2 * k0 + 1] = ai - bi;   // X[k0+4]
    }
}

// One block per ROW PAIR: z = g0*x0 + i*g1*x1, 4096-pt FFT (radix-8 x 4,
// 512 threads), wave-local top-8 per row straight from Z, sparse inverse.
__global__ __launch_bounds__(THREADS, 8)
void fft2_topk_k(const float* __restrict__ x, const float* __restrict__ te,
                 const float* __restrict__ W, const float* __restrict__ bias,
                 float* __restrict__ out) {
    __shared__ float re[LL], im[LL];
    __shared__ float wv[8];
    __shared__ float selA[2][KK], selB[2][KK];
    __shared__ int   selF[2][KK];

    int t = threadIdx.x;
    int pair = blockIdx.x;
    int b = pair >> 6;
    int c0 = (pair & 63) << 1;
    int row0 = (b << 7) + c0;

    // modulation dots: threads<256 -> row0, >=256 -> row1 (256 thr x 2 terms)
    {
        int half = t >> 8, tt = t & 255;
        const float* tp = te + b * 512;
        const float* wp = W + (c0 + half) * 512;
        float ps = tp[tt] * wp[tt] + tp[tt + 256] * wp[tt + 256];
#pragma unroll
        for (int off = 32; off; off >>= 1) ps += __shfl_down(ps, off);
        if ((t & 63) == 0) wv[t >> 6] = ps;
    }

    const float* xp0 = x + (size_t)row0 * LL;
    const float* xp1 = xp0 + LL;
    float vr[8], vi[8];
#pragma unroll
    for (int r = 0; r < 8; ++r) { vr[r] = xp0[t + 512 * r]; vi[r] = xp1[t + 512 * r]; }
    __syncthreads();
    float g0 = 1.0f + tanhf(wv[0] + wv[1] + wv[2] + wv[3] + bias[c0]);
    float g1 = 1.0f + tanhf(wv[4] + wv[5] + wv[6] + wv[7] + bias[c0 + 1]);
#pragma unroll
    for (int r = 0; r < 8; ++r) { vr[r] *= g0; vi[r] *= g1; }

    // ---- pass 0 (Ns=1): no twiddle ----
    dft8(vr, vi);
#pragma unroll
    for (int r = 0; r < 8; ++r) {
        int d = SW(t * 8 + r);
        re[d] = vr[PERM8(r)]; im[d] = vi[PERM8(r)];
    }
    __syncthreads();

    // ---- pass 1 (Ns=8) ----
#pragma unroll
    for (int r = 0; r < 8; ++r) {
        int a = SW(t + 512 * r);
        vr[r] = re[a]; vi[r] = im[a];
    }
    {
        int ns = t & 7;
        const float i64 = 1.0f / 64.0f;
#pragma unroll
        for (int r = 1; r < 8; ++r) {
            float v = (float)(ns * r) * i64;        // exact
            cmulw(vr[r], vi[r], cosr(v), sinr(v));
        }
    }
    dft8(vr, vi);
    __syncthreads();
    {
        int base = ((t >> 3) << 6) + (t & 7);
#pragma unroll
        for (int r = 0; r < 8; ++r) {
            int d = SW(base + 8 * r);
            re[d] = vr[PERM8(r)]; im[d] = vi[PERM8(r)];
        }
    }
    __syncthreads();

    // ---- pass 2 (Ns=64) ----
#pragma unroll
    for (int r = 0; r < 8; ++r) {
        int a = SW(t + 512 * r);
        vr[r] = re[a]; vi[r] = im[a];
    }
    {
        int ns = t & 63;
        const float i512 = 1.0f / 512.0f;
#pragma unroll
        for (int r = 1; r < 8; ++r) {
            float v = (float)(ns * r) * i512;       // exact
            cmulw(vr[r], vi[r], cosr(v), sinr(v));
        }
    }
    dft8(vr, vi);
    __syncthreads();
    {
        int base = ((t >> 6) << 9) + (t & 63);
#pragma unroll
        for (int r = 0; r < 8; ++r) {
            int d = SW(base + 64 * r);
            re[d] = vr[PERM8(r)]; im[d] = vi[PERM8(r)];
        }
    }
    __syncthreads();

    // ---- pass 3 (Ns=512): natural-order Z -> LDS ----
#pragma unroll
    for (int r = 0; r < 8; ++r) {
        int a = SW(t + 512 * r);
        vr[r] = re[a]; vi[r] = im[a];
    }
    {
        const float i4096 = 1.0f / 4096.0f;
#pragma unroll
        for (int r = 1; r < 8; ++r) {
            float v = (float)(t * r) * i4096;       // t*r <= 3577, exact
            cmulw(vr[r], vi[r], cosr(v), sinr(v));
        }
    }
    dft8(vr, vi);
    __syncthreads();
#pragma unroll
    for (int r = 0; r < 8; ++r) {
        int d = SW(t + 512 * r);
        re[d] = vr[PERM8(r)]; im[d] = vi[PERM8(r)];
    }
    __syncthreads();

    // ---- wave-local top-8: wave 0 -> row0, wave 1 -> row1 ----
    // amp computed on the fly from Z: X1=(Z[k]+conj(Z[-k]))/2,
    // X2=-i(Z[k]-conj(Z[-k]))/2. Lane l owns bins l+64m, m=0..31 (+2048 on l0).
    {
        int wid = t >> 6, lane = t & 63;
        if (wid < 2) {
            float amp[33];
#pragma unroll
            for (int m = 0; m < 33; ++m) {
                int k = lane + (m << 6);
                int a1 = SW(k & 4095), a2 = SW((4096 - k) & 4095);
                float zr = re[a1], zi = im[a1];
                float yr = re[a2], yi = im[a2];
                float Xr, Xi;
                if (wid == 0) { Xr = 0.5f * (zr + yr); Xi = 0.5f * (zi - yi); }
                else          { Xr = 0.5f * (zi + yi); Xi = 0.5f * (yr - zr); }
                bool ok = (m < 32) || (lane == 0);  // m==32: only bin 2048
                amp[m] = ok ? (Xr * Xr + Xi * Xi) : -1.f;
            }
            for (int it = 0; it < KK; ++it) {
                float bv = -1.f; int bm = 0;
#pragma unroll
                for (int m = 0; m < 33; ++m)        // ascending m: lower bin on tie
                    if (amp[m] > bv) { bv = amp[m]; bm = m; }
                int bf = lane + (bm << 6);
#pragma unroll
                for (int off = 32; off; off >>= 1) {
                    float ov = __shfl_down(bv, off);
                    int   of = __shfl_down(bf, off);
                    if (ov > bv || (ov == bv && of < bf)) { bv = ov; bf = of; }
                }
                bf = __shfl(bf, 0);                 // broadcast winner bin
                if ((bf & 63) == lane) {            // owner removes it
                    int sm = bf >> 6;
#pragma unroll
                    for (int m = 0; m < 33; ++m)
                        if (m == sm) amp[m] = -1.f;
                }
                if (lane == 0) {                    // recompute X(bf), record
                    int a1 = SW(bf), a2 = SW((4096 - bf) & 4095);
                    float zr = re[a1], zi = im[a1];
                    float yr = re[a2], yi = im[a2];
                    float Xr, Xi;
                    if (wid == 0) { Xr = 0.5f * (zr + yr); Xi = 0.5f * (zi - yi); }
                    else          { Xr = 0.5f * (zi + yi); Xi = 0.5f * (yr - zr); }
                    bool edge = (bf == 0) || (bf == 2048);
                    float wgt = edge ? 1.f : 2.f;
                    selF[wid][it] = bf;
                    selA[wid][it] = wgt * (1.0f / 4096.0f) * Xr;
                    selB[wid][it] = edge ? 0.f : wgt * (1.0f / 4096.0f) * Xi;
                }
            }
        }
    }
    __syncthreads();

    // ---- sparse inverse: threads<256 -> row0, >=256 -> row1 ----
    // w_k[n] = (A+iB) e^{2pi i f n/L}; out[n]=sum Re(w_k); out[n+2048] uses
    // (-1)^f. 8 rotator steps of 256 samples each.
    {
        int half = t >> 8, u = t & 255;
        float wr_[KK], wj_[KK], cS[KK], sS[KK], sg[KK];
        const float i4096 = 1.0f / 4096.0f;
#pragma unroll
        for (int k = 0; k < KK; ++k) {
            int f = selF[half][k];
            float A = selA[half][k], Bv = selB[half][k];
            int m0 = (f * u) & 4095;
            float c0_ = cosr((float)m0 * i4096), s0_ = sinr((float)m0 * i4096);
            wr_[k] = A * c0_ - Bv * s0_;
            wj_[k] = A * s0_ + Bv * c0_;
            int ms = (f & 15) << 8;                 // step: 256 samples
            cS[k] = cosr((float)ms * i4096);
            sS[k] = sinr((float)ms * i4096);
            sg[k] = (f & 1) ? -1.f : 1.f;
        }
        float* op = out + (size_t)(row0 + half) * LL;
#pragma unroll 1
        for (int q = 0; q < 8; ++q) {
            float acc = 0.f, acd = 0.f;
#pragma unroll
            for (int k = 0; k < KK; ++k) {
                acc += wr_[k];
                acd = fmaf(sg[k], wr_[k], acd);
                float nc = wr_[k] * cS[k] - wj_[k] * sS[k];
                float ni = wj_[k] * cS[k] + wr_[k] * sS[k];
                wr_[k] = nc; wj_[k] = ni;
            }
            op[u + (q << 8)] = acc;
            op[u + (q << 8) + 2048] = acd;
        }
    }
}

extern "C" void kernel_launch(void* const* d_in, const int* in_sizes, int n_in,
                              void* d_out, int out_size, void* d_ws, size_t ws_size,
                              hipStream_t stream) {
    const float* x    = (const float*)d_in[0];
    const float* te   = (const float*)d_in[1];
    const float* W    = (const float*)d_in[2];
    const float* bias = (const float*)d_in[3];
    float* out = (float*)d_out;
    fft2_topk_k<<<2048, THREADS, 0, stream>>>(x, te, W, bias, out);
}

// Round 6
// 62.425 us; speedup vs baseline: 4.7332x; 1.0228x over previous
//
#include <hip/hip_runtime.h>

#define LL 4096
#define THREADS 512
#define KK 8

typedef float v2f __attribute__((ext_vector_type(2)));

// XOR swizzle for 8-byte LDS elements: all FFT patterns uniform over bank pairs.
#define SW(i) ((i) ^ (((i) >> 3) & 15))
// dft8: X[k0+4*k1] sits in slot 2*k0+k1 -> slot holding X[r]:
#define PERM8(r) ((((r) & 3) << 1) | ((r) >> 2))

// HW trig, input in REVOLUTIONS: sinr(x)=sin(2*pi*x). All args are exact
// m/2^k in [0,1), so no range-reduction error.
__device__ __forceinline__ float sinr(float x) {
    float r; asm("v_sin_f32 %0, %1" : "=v"(r) : "v"(x)); return r;
}
__device__ __forceinline__ float cosr(float x) {
    float r; asm("v_cos_f32 %0, %1" : "=v"(r) : "v"(x)); return r;
}

// twiddle apply: multiply z=(zr,zi) by (c - i*s), w=(c,s)
__device__ __forceinline__ v2f cmulw(v2f z, v2f w) {
    v2f zs = __builtin_shufflevector(z, z, 1, 0);      // (zi, zr)
    v2f res = z * (v2f){w.x, w.x};
    res += zs * (v2f){w.y, -w.y};
    return res;
}
// standard complex multiply (a.x+i a.y)(b.x+i b.y) — recurrence & rotators
__device__ __forceinline__ v2f cmul(v2f a, v2f b) {
    v2f as = __builtin_shufflevector(a, a, 1, 0);
    v2f res = a * (v2f){b.x, b.x};
    res += as * (v2f){-b.y, b.y};
    return res;
}

// forward 4-point DFT (w4 = -i), in place, complex-packed
__device__ __forceinline__ void dft4(v2f& a, v2f& b, v2f& c, v2f& d) {
    v2f t0 = a + c, t1 = a - c, t2 = b + d, t3 = b - d;
    a = t0 + t2; c = t0 - t2;
    v2f t3n = (v2f){t3.y, -t3.x};   // -i * t3
    b = t1 + t3n; d = t1 - t3n;
}

// forward 8-point DFT; output permuted per PERM8
__device__ __forceinline__ void dft8(v2f* v) {
    dft4(v[0], v[2], v[4], v[6]);
    dft4(v[1], v[3], v[5], v[7]);
    const float C2 = 0.70710678118654752f;
    v[3] = cmulw(v[3], (v2f){C2, C2});     // w8^1
    v[5] = (v2f){v[5].y, -v[5].x};         // w8^2 = -i
    v[7] = cmulw(v[7], (v2f){-C2, C2});    // w8^3
#pragma unroll
    for (int k0 = 0; k0 < 4; ++k0) {
        v2f a = v[2 * k0], b = v[2 * k0 + 1];
        v[2 * k0]     = a + b;
        v[2 * k0 + 1] = a - b;
    }
}

// apply twiddles w^r (r=1..7) for base angle th (revolutions) via recurrence:
// 2 HW trig + 6 complex muls instead of 14 trig.
__device__ __forceinline__ void twiddle7(v2f* v, float th) {
    v2f w1 = (v2f){cosr(th), sinr(th)};
    v2f w = w1;
    v[1] = cmulw(v[1], w);
#pragma unroll
    for (int r = 2; r < 8; ++r) {
        w = cmul(w, w1);
        v[r] = cmulw(v[r], w);
    }
}

// One block per ROW PAIR: z = g0*x0 + i*g1*x1, 4096-pt FFT (radix-8 x 4,
// 512 threads, packed-f32 complex), wave-local top-8 per row, sparse inverse.
__global__ __launch_bounds__(THREADS, 8)
void fft2_topk_k(const float* __restrict__ x, const float* __restrict__ te,
                 const float* __restrict__ W, const float* __restrict__ bias,
                 float* __restrict__ out) {
    __shared__ v2f zb[LL];                  // 32 KB
    __shared__ float wv[8];
    __shared__ v2f  selAB[2][KK];           // (A, B)
    __shared__ v2f  selST[2][KK];           // rotator step (cos, sin)
    __shared__ int  selF[2][KK];

    int t = threadIdx.x;
    int pair = blockIdx.x;
    int b = pair >> 6;
    int c0 = (pair & 63) << 1;
    int row0 = (b << 7) + c0;

    // modulation dots: threads<256 -> row0, >=256 -> row1
    {
        int half = t >> 8, tt = t & 255;
        const float* tp = te + b * 512;
        const float* wp = W + (c0 + half) * 512;
        float ps = tp[tt] * wp[tt] + tp[tt + 256] * wp[tt + 256];
#pragma unroll
        for (int off = 32; off; off >>= 1) ps += __shfl_down(ps, off);
        if ((t & 63) == 0) wv[t >> 6] = ps;
    }

    const float* xp0 = x + (size_t)row0 * LL;
    const float* xp1 = xp0 + LL;
    v2f v[8];
#pragma unroll
    for (int r = 0; r < 8; ++r) { v[r].x = xp0[t + 512 * r]; v[r].y = xp1[t + 512 * r]; }
    __syncthreads();
    float g0 = 1.0f + tanhf(wv[0] + wv[1] + wv[2] + wv[3] + bias[c0]);
    float g1 = 1.0f + tanhf(wv[4] + wv[5] + wv[6] + wv[7] + bias[c0 + 1]);
    {
        v2f g = (v2f){g0, g1};
#pragma unroll
        for (int r = 0; r < 8; ++r) v[r] *= g;
    }

    // ---- pass 0 (Ns=1): no twiddle ----
    dft8(v);
#pragma unroll
    for (int r = 0; r < 8; ++r) zb[SW(t * 8 + r)] = v[PERM8(r)];
    __syncthreads();

    // ---- pass 1 (Ns=8) ----
#pragma unroll
    for (int r = 0; r < 8; ++r) v[r] = zb[SW(t + 512 * r)];
    twiddle7(v, (float)(t & 7) * (1.0f / 64.0f));
    dft8(v);
    __syncthreads();
    {
        int base = ((t >> 3) << 6) + (t & 7);
#pragma unroll
        for (int r = 0; r < 8; ++r) zb[SW(base + 8 * r)] = v[PERM8(r)];
    }
    __syncthreads();

    // ---- pass 2 (Ns=64) ----
#pragma unroll
    for (int r = 0; r < 8; ++r) v[r] = zb[SW(t + 512 * r)];
    twiddle7(v, (float)(t & 63) * (1.0f / 512.0f));
    dft8(v);
    __syncthreads();
    {
        int base = ((t >> 6) << 9) + (t & 63);
#pragma unroll
        for (int r = 0; r < 8; ++r) zb[SW(base + 64 * r)] = v[PERM8(r)];
    }
    __syncthreads();

    // ---- pass 3 (Ns=512): natural-order Z ----
#pragma unroll
    for (int r = 0; r < 8; ++r) v[r] = zb[SW(t + 512 * r)];
    twiddle7(v, (float)t * (1.0f / 4096.0f));
    dft8(v);
    __syncthreads();
#pragma unroll
    for (int r = 0; r < 8; ++r) zb[SW(t + 512 * r)] = v[PERM8(r)];
    __syncthreads();

    // ---- wave-local top-8: wave 0 -> row0, wave 1 -> row1 ----
    // X1=(Z[k]+conj(Z[-k]))/2, X2=-i(Z[k]-conj(Z[-k]))/2 (covers k=0,2048 too).
    {
        int wid = t >> 6, lane = t & 63;
        if (wid < 2) {
            float amp[33];
#pragma unroll
            for (int m = 0; m < 33; ++m) {
                int k = lane + (m << 6);
                v2f z = zb[SW(k & 4095)];
                v2f y = zb[SW((4096 - k) & 4095)];
                v2f X;
                if (wid == 0) X = (v2f){0.5f * (z.x + y.x), 0.5f * (z.y - y.y)};
                else          X = (v2f){0.5f * (z.y + y.y), 0.5f * (y.x - z.x)};
                bool ok = (m < 32) || (lane == 0);  // m==32: only bin 2048
                amp[m] = ok ? (X.x * X.x + X.y * X.y) : -1.f;
            }
            for (int it = 0; it < KK; ++it) {
                float bv = -1.f; int bm = 0;
#pragma unroll
                for (int m = 0; m < 33; ++m)        // ascending m: lower bin on tie
                    if (amp[m] > bv) { bv = amp[m]; bm = m; }
                int bf = lane + (bm << 6);
#pragma unroll
                for (int off = 32; off; off >>= 1) {
                    float ov = __shfl_down(bv, off);
                    int   of = __shfl_down(bf, off);
                    if (ov > bv || (ov == bv && of < bf)) { bv = ov; bf = of; }
                }
                bf = __shfl(bf, 0);                 // broadcast winner bin
                if ((bf & 63) == lane) {            // owner removes it
                    int sm = bf >> 6;
#pragma unroll
                    for (int m = 0; m < 33; ++m)
                        if (m == sm) amp[m] = -1.f;
                }
                if (lane == 0) {                    // recompute X(bf), record
                    v2f z = zb[SW(bf)];
                    v2f y = zb[SW((4096 - bf) & 4095)];
                    v2f X;
                    if (wid == 0) X = (v2f){0.5f * (z.x + y.x), 0.5f * (z.y - y.y)};
                    else          X = (v2f){0.5f * (z.y + y.y), 0.5f * (y.x - z.x)};
                    bool edge = (bf == 0) || (bf == 2048);
                    float wgt = edge ? 1.f : 2.f;
                    selF[wid][it] = bf;
                    selAB[wid][it] = (v2f){wgt * (1.0f / 4096.0f) * X.x,
                                           edge ? 0.f : wgt * (1.0f / 4096.0f) * X.y};
                    float a = (float)((bf & 15) << 8) * (1.0f / 4096.0f);
                    selST[wid][it] = (v2f){cosr(a), sinr(a)};   // step e^{+i*2pi*a}
                }
            }
        }
    }
    __syncthreads();

    // ---- sparse inverse: threads<256 -> row0, >=256 -> row1 ----
    // w_k[n] = (A+iB) e^{2pi i f n/L}; out[n]=sum Re(w_k); out[n+2048] via
    // (-1)^f. 8 rotator steps of 256 samples each.
    {
        int half = t >> 8, u = t & 255;
        v2f w[KK], st[KK]; float sg[KK];
        const float i4096 = 1.0f / 4096.0f;
#pragma unroll
        for (int k = 0; k < KK; ++k) {
            int f = selF[half][k];
            int m0 = (f * u) & 4095;
            float a0 = (float)m0 * i4096;
            w[k] = cmul(selAB[half][k], (v2f){cosr(a0), sinr(a0)});
            st[k] = selST[half][k];
            sg[k] = (f & 1) ? -1.f : 1.f;
        }
        float* op = out + (size_t)(row0 + half) * LL;
#pragma unroll 1
        for (int q = 0; q < 8; ++q) {
            float acc = 0.f, acd = 0.f;
#pragma unroll
            for (int k = 0; k < KK; ++k) {
                acc += w[k].x;
                acd = fmaf(sg[k], w[k].x, acd);
                w[k] = cmul(w[k], st[k]);
            }
            op[u + (q << 8)] = acc;
            op[u + (q << 8) + 2048] = acd;
        }
    }
}

extern "C" void kernel_launch(void* const* d_in, const int* in_sizes, int n_in,
                              void* d_out, int out_size, void* d_ws, size_t ws_size,
                              hipStream_t stream) {
    const float* x    = (const float*)d_in[0];
    const float* te   = (const float*)d_in[1];
    const float* W    = (const float*)d_in[2];
    const float* bias = (const float*)d_in[3];
    float* out = (float*)d_out;
    fft2_topk_k<<<2048, THREADS, 0, stream>>>(x, te, W, bias, out);
}